// Round 5
// baseline (61.612 us; speedup 1.0000x reference)
//
#include <hip/hip_runtime.h>
#include <math.h>

#define DIM 4096
#define BATCH 64

typedef __attribute__((ext_vector_type(8))) short short8;
typedef __attribute__((ext_vector_type(4))) float f32x4;
typedef __attribute__((ext_vector_type(4))) unsigned int u32x4;

__device__ __forceinline__ float4 ld4(const float* p) {
    return *reinterpret_cast<const float4*>(p);
}

// f32 -> bf16 bits, round-to-nearest-even (used off the hot path)
__device__ __forceinline__ unsigned short f2bf(float f) {
    unsigned u = __builtin_bit_cast(unsigned, f);
    u = (u + 0x7fffu + ((u >> 16) & 1u)) >> 16;
    return (unsigned short)u;
}

// pack two f32 -> one u32 of two bf16 (truncation; cheap, 3 VALU ops)
__device__ __forceinline__ unsigned pack_bf2(float x, float y) {
    return (__builtin_bit_cast(unsigned, x) >> 16) |
           (__builtin_bit_cast(unsigned, y) & 0xffff0000u);
}

// K1: L2-normalize rows of input_x; emit bf16 in MFMA fragment orders.
//   MFMA 16x16x32 bf16 (verified, learn_hip m89):
//     A: lane l, reg j -> A[l&15][(l>>4)*8 + j]
//     B: lane l, reg j -> B[(l>>4)*8 + j][l&15]
//     D: lane l, reg q -> D[(l>>4)*4 + q][l&15]
// xb1: B-frags for phase 1 (y = W @ xnT): K-dim = k, col = b.
//   layout: [bt(4)][kstep(128)][lane(64)] x short8
// xa2: A-frags for phase 2 (d^T = xn^T-tile @ (NC*y)^T): A[j][b] = xn[b][jcol].
//   layout: [jt(256)][ks(2)][lane(64)] x short8
//   element: lane l, reg r -> xn[ks*32 + (l>>4)*8 + r][jt*16 + (l&15)]
__global__ __launch_bounds__(256) void k_norm(const float* __restrict__ x,
                                              unsigned short* __restrict__ xb1,
                                              unsigned short* __restrict__ xa2) {
    const int b = blockIdx.x;
    const int tid = threadIdx.x;
    const float* row = x + (size_t)b * DIM;

    float ss = 0.f;
    for (int k = tid * 4; k < DIM; k += 256 * 4) {
        float4 v = ld4(row + k);
        ss += v.x * v.x + v.y * v.y + v.z * v.z + v.w * v.w;
    }
#pragma unroll
    for (int m = 32; m >= 1; m >>= 1) ss += __shfl_xor(ss, m, 64);

    __shared__ float wsum[4];
    if ((tid & 63) == 0) wsum[tid >> 6] = ss;
    __syncthreads();
    const float total = wsum[0] + wsum[1] + wsum[2] + wsum[3];
    const float scale = 1.0f / (sqrtf(total) + 1e-8f);

    // xb1 coords from b
    const int bt = b >> 4;            // b-tile
    const int li = b & 15;            // col-in-tile
    // xa2 coords from b (b is the K index)
    const int ks  = b >> 5;           // K-step (0/1)
    const int bhi = (b >> 3) & 3;     // lane-high bits
    const int br  = b & 7;            // reg index

    for (int k = tid; k < DIM; k += 256) {
        const float v = row[k] * scale;
        const unsigned short h = f2bf(v);
        // xb1 (k is the K-dim)
        const int l1 = li | (((k & 31) >> 3) << 4);
        xb1[(size_t)((((bt * 128) + (k >> 5)) * 64 + l1) << 3) + (k & 7)] = h;
        // xa2 (k is the output-column dim j)
        const int l2 = (k & 15) | (bhi << 4);
        xa2[(size_t)(((((k >> 4) * 2) + ks) * 64 + l2) << 3) + br] = h;
    }
}

// Fused: per 16-row tile of W:
//   phase 1: y[16][64] = W_rows @ xnT   (split-K over 16 waves, MFMA, LDS-reduce)
//   phase 2: out = W - lr*G + d, where d^T-tiles = xa2 @ ya  -> D-layout lands
//            with lane = W-row and regs = 4 consecutive output cols: pure
//            float4 load-modify-store epilogue, no LDS, no barriers.
__global__ __launch_bounds__(1024, 4) void k_fused(const float* __restrict__ W,
                                                   const float* __restrict__ G,
                                                   const unsigned short* __restrict__ xb1,
                                                   const unsigned short* __restrict__ xa2,
                                                   float* __restrict__ out) {
    __shared__ __align__(16) float yp[16 * 4 * 64 * 4];  // 64 KB phase-1 partials
    __shared__ float y2[16 * 68];                        // reduced y, padded

    const int tid = threadIdx.x;
    const int wv = tid >> 6;      // wave 0..15
    const int l  = tid & 63;      // lane
    const int lr = l & 15;
    const int lh = l >> 4;
    const int i0 = blockIdx.x * 16;

    // ---------------- phase 1: y = W_rows @ xnT, wave wv covers K [wv*256, +256)
    f32x4 acc0 = {0.f, 0.f, 0.f, 0.f};
    f32x4 acc1 = acc0, acc2 = acc0, acc3 = acc0;
    const short8* xb1v = (const short8*)xb1;

#pragma unroll 2
    for (int s = 0; s < 8; ++s) {
        const int kbg = wv * 8 + s;
        const float* wp = W + (size_t)(i0 + lr) * DIM + kbg * 32 + lh * 8;
        const float4 wa = ld4(wp);
        const float4 wb = ld4(wp + 4);
        const int bs = kbg * 64 + l;
        const short8 b0 = xb1v[bs];
        const short8 b1 = xb1v[bs + 8192];
        const short8 b2 = xb1v[bs + 16384];
        const short8 b3 = xb1v[bs + 24576];
        u32x4 ap;
        ap[0] = pack_bf2(wa.x, wa.y);
        ap[1] = pack_bf2(wa.z, wa.w);
        ap[2] = pack_bf2(wb.x, wb.y);
        ap[3] = pack_bf2(wb.z, wb.w);
        const short8 a = __builtin_bit_cast(short8, ap);
        acc0 = __builtin_amdgcn_mfma_f32_16x16x32_bf16(a, b0, acc0, 0, 0, 0);
        acc1 = __builtin_amdgcn_mfma_f32_16x16x32_bf16(a, b1, acc1, 0, 0, 0);
        acc2 = __builtin_amdgcn_mfma_f32_16x16x32_bf16(a, b2, acc2, 0, 0, 0);
        acc3 = __builtin_amdgcn_mfma_f32_16x16x32_bf16(a, b3, acc3, 0, 0, 0);
    }
    {
        f32x4* dst = (f32x4*)yp;
        dst[(wv * 4 + 0) * 64 + l] = acc0;
        dst[(wv * 4 + 1) * 64 + l] = acc1;
        dst[(wv * 4 + 2) * 64 + l] = acc2;
        dst[(wv * 4 + 3) * 64 + l] = acc3;
    }
    __syncthreads();

    // reduce 16 partials: thread t owns y element (r = t>>6, b = t&63)
    {
        const int r  = tid >> 6;
        const int bb = tid & 63;
        const int btt = bb >> 4;
        const int lii = (bb & 15) | ((r >> 2) << 4);
        const int jq  = r & 3;
        float s = 0.f;
#pragma unroll
        for (int w = 0; w < 16; ++w) s += yp[(((w * 4 + btt) * 64 + lii) << 2) + jq];
        y2[r * 68 + bb] = s;
    }
    __syncthreads();

    // B-fragments for phase 2: B[b][i] = NC * y[i][b]  (i.e. ya0/ya1 = NC*y^T)
    const float NC = -0.01f / 64.0f;
    short8 ya0, ya1;
#pragma unroll
    for (int j = 0; j < 8; ++j) {
        ya0[j] = (short)f2bf(NC * y2[lr * 68 + lh * 8 + j]);
        ya1[j] = (short)f2bf(NC * y2[lr * 68 + 32 + lh * 8 + j]);
    }

    // ---------------- phase 2: wave wv owns cols [wv*256, +256), 16 jt-tiles.
    // d^T = A·B with A = xa2 (16 j x 32 b), B = NC*y^T (32 b x 16 i):
    //   D[(l>>4)*4+q][l&15] = d[i = l&15][j = jt*16 + (l>>4)*4 + q]
    // -> lane l: row i0+(l&15), 4 consecutive cols at jt*16+(l>>4)*4.
    constexpr float LRc = 0.001f;
    const short8* xa2v = (const short8*)xa2;
#pragma unroll 4
    for (int t = 0; t < 16; ++t) {
        const int jt = wv * 16 + t;
        const short8 a0 = xa2v[(jt * 2 + 0) * 64 + l];
        const short8 a1 = xa2v[(jt * 2 + 1) * 64 + l];
        f32x4 d = {0.f, 0.f, 0.f, 0.f};
        d = __builtin_amdgcn_mfma_f32_16x16x32_bf16(a0, ya0, d, 0, 0, 0);
        d = __builtin_amdgcn_mfma_f32_16x16x32_bf16(a1, ya1, d, 0, 0, 0);
        const size_t idx = (size_t)(i0 + lr) * DIM + jt * 16 + lh * 4;
        const float4 w4 = ld4(W + idx);
        const float4 g4 = ld4(G + idx);
        float4 o;
        o.x = w4.x - LRc * g4.x + d[0];
        o.y = w4.y - LRc * g4.y + d[1];
        o.z = w4.z - LRc * g4.z + d[2];
        o.w = w4.w - LRc * g4.w + d[3];
        *reinterpret_cast<float4*>(out + idx) = o;
    }
}

extern "C" void kernel_launch(void* const* d_in, const int* in_sizes, int n_in,
                              void* d_out, int out_size, void* d_ws, size_t ws_size,
                              hipStream_t stream) {
    const float* W = (const float*)d_in[0];   // weight  (DIM x DIM)
    const float* X = (const float*)d_in[1];   // input_x (BATCH x DIM)
    const float* G = (const float*)d_in[2];   // grad    (DIM x DIM)
    float* out = (float*)d_out;

    unsigned short* xb1 = (unsigned short*)d_ws;               // DIM*BATCH bf16 (512 KB)
    unsigned short* xa2 = xb1 + (size_t)DIM * BATCH;           // DIM*BATCH bf16 (512 KB)

    hipLaunchKernelGGL(k_norm, dim3(BATCH), dim3(256), 0, stream, X, xb1, xa2);
    hipLaunchKernelGGL(k_fused, dim3(DIM / 16), dim3(1024), 0, stream,
                       W, G, xb1, xa2, out);
}